// Round 14
// baseline (226.582 us; speedup 1.0000x reference)
//
#include <hip/hip_runtime.h>

// ARMA GNN (T=1,K=1) x2 layers on MI355X — chunk-major partition (fused
// rank-replay sorts) + degree-grouped bf16-packed gather.
// (Resubmission of round-13 kernel: container infra failure, no bench signal.)
//
// Round-12 lessons: gather invariant to slots/occupancy/tail fixes -> last
// untested axis is WAVE IMBALANCE (runtime = max over 16 nodes' ceil(deg/16),
// deg~Po(32) -> ~2x mean). Fix: process nodes in degree-grouped order (perm
// from a counting sort by clamped degree). Sort kernels: replace 2-pass
// (histogram + atomic-scatter) with 1-pass rank-recording (LDS atomicAdd
// returns within-segment rank; replay from static-indexed register arrays).
//
// Pipeline (built once, reused by both layers):
//   CS chunk_sort:  block i (1024 thr) one-pass counting-sorts its 12500-edge
//                   chunk by bucket; srt CHUNK-MAJOR + histg/segst tables.
//   T  tot8 / S scan1024: bucket totals -> bucket_base
//   BS bucket_sort: per bucket: segments -> LDS stage, rank-recorded col sort
//                   -> ptr/dinv/srt2 (CSR).
//   D  deg_hist/deg_scan/deg_scatter: counting sort of nodes by min(deg,255)
//                   -> perm (degree-grouped node order).
// Per layer:
//   proj:   p[i] = pack_bf16x2((h[i] @ W) * dinv[i])   (p overlays dead srt)
//   gather: 4 lanes/node, nodes in perm order, predicated unroll-8, fp32
//           accum, shfl_xor combine, fused h@V+b+relu, float4 stores.

#define WC 128          // bucket width (cols)
#define LG2WC 7
#define MAXB 1024       // padded bucket count (supports n up to 131072)
#define NBC 256         // partition chunks
#define SCAP 8192       // bucket_sort LDS stage capacity
#define CITER 13        // ceil(chunkE/1024), chunkE = 12500
#define SITER 32        // SCAP/256

typedef unsigned uintv4 __attribute__((ext_vector_type(4)));

__device__ inline unsigned bf16rte(float x) {
    unsigned u = __float_as_uint(x);
    return (u + 0x7FFFu + ((u >> 16) & 1u)) >> 16;
}

// Block i (1024 threads): ONE-PASS counting sort of its chunk by bucket.
// Pass: histogram with rank recording (static register arrays); scan; replay.
__global__ __launch_bounds__(1024)
void chunk_sort(const int* __restrict__ row, const int* __restrict__ col,
                int* __restrict__ srt, int* __restrict__ histg,
                int* __restrict__ segst, int E, int B, int chunkE) {
    __shared__ int hist[MAXB];
    __shared__ int cur[MAXB];
    __shared__ int tsum[MAXB];
    int i = blockIdx.x, t = threadIdx.x;
    hist[t] = 0;
    __syncthreads();
    int lo = i * chunkE, hi = lo + chunkE; if (hi > E) hi = E;
    int pk_[CITER];
    unsigned br_[CITER];
#pragma unroll
    for (int q = 0; q < CITER; q++) {
        int e = lo + t + q * 1024;
        int pkv = 0; unsigned brv = 0xFFFFFFFFu;
        if (e < hi) {
            int c = col[e];
            int r = row[e];
            int bkt = c >> LG2WC;
            int rank = atomicAdd(&hist[bkt], 1);       // LDS; rank within (chunk,bucket)
            pkv = ((c & (WC - 1)) << 17) | r;          // row<2^17, lcol bits 17..23
            brv = (unsigned)bkt | ((unsigned)rank << 10);
        }
        pk_[q] = pkv; br_[q] = brv;
    }
    __syncthreads();
    // exclusive scan hist[0..1024) -> cur (1 elem/thread Hillis-Steele)
    int v = hist[t];
    tsum[t] = v;
    __syncthreads();
    for (int off = 1; off < 1024; off <<= 1) {
        int u = 0;
        if (t >= off) u = tsum[t - off];
        __syncthreads();
        if (t >= off) tsum[t] += u;
        __syncthreads();
    }
    cur[t] = tsum[t] - v;
    __syncthreads();
    // write tables (chunk-major, coalesced)
    if (t < B) {
        histg[(size_t)i * B + t] = hist[t];
        segst[(size_t)i * B + t] = cur[t];
    }
    // replay: position = window base + bucket base + recorded rank
#pragma unroll
    for (int q = 0; q < CITER; q++) {
        if (br_[q] != 0xFFFFFFFFu) {
            int bkt = br_[q] & 1023;
            int rank = (int)(br_[q] >> 10);
            srt[lo + cur[bkt] + rank] = pk_[q];
        }
    }
}

// part[k*B+j] = sum_{i in slice k} histg[i*B+j]; 8 slices of 32 chunks.
__global__ void tot8_kernel(const int* __restrict__ histg, int* __restrict__ part, int B) {
    int idx = blockIdx.x * blockDim.x + threadIdx.x;
    if (idx >= 8 * B) return;
    int k = idx / B, j = idx - k * B;
    int s = 0;
    for (int i = k * 32; i < k * 32 + 32; i++) s += histg[(size_t)i * B + j];
    part[(size_t)k * B + j] = s;
}

__global__ void scan1024_kernel(const int* __restrict__ part, int* __restrict__ base, int B) {
    __shared__ int s[1024];
    int t = threadIdx.x;
    int v = 0;
    if (t < B) {
#pragma unroll
        for (int k = 0; k < 8; k++) v += part[(size_t)k * B + t];
    }
    s[t] = v;
    __syncthreads();
    for (int off = 1; off < 1024; off <<= 1) {
        int u = 0;
        if (t >= off) u = s[t - off];
        __syncthreads();
        if (t >= off) s[t] += u;
        __syncthreads();
    }
    if (t < B) base[t] = s[t] - v;  // exclusive
}

// Per bucket: segments -> LDS stage; one-pass rank-recorded col sort -> srt2.
__global__ void bucket_sort(const int* __restrict__ srt, const int* __restrict__ histg,
                            const int* __restrict__ segst, const int* __restrict__ bbase,
                            int* __restrict__ ptr, int* __restrict__ srt2,
                            float* __restrict__ dinv, int E, int n, int B, int chunkE) {
    __shared__ int hrow[NBC];
    __shared__ int srow[NBC];
    __shared__ int spref[NBC];
    __shared__ int stage[SCAP];
    __shared__ int tsum[256];
    __shared__ int cnt[WC], colb[WC], cexc[WC];
    __shared__ int Ssh;
    int j = blockIdx.x, t = threadIdx.x;
    hrow[t] = histg[(size_t)t * B + j];
    srow[t] = segst[(size_t)t * B + j];
    if (t < WC) cnt[t] = 0;
    __syncthreads();
    // exclusive scan hrow[0..256) -> spref
    int v = hrow[t];
    tsum[t] = v;
    __syncthreads();
    for (int off = 1; off < 256; off <<= 1) {
        int u = 0;
        if (t >= off) u = tsum[t - off];
        __syncthreads();
        if (t >= off) tsum[t] += u;
        __syncthreads();
    }
    spref[t] = tsum[t] - v;
    if (t == 255) Ssh = tsum[255];
    __syncthreads();
    int S = Ssh;                 // bucket size (block-uniform)
    int gbase = bbase[j];
    bool fits = (S <= SCAP);     // uniform branch (S ~ Po(4096), SCAP=8192)
    int rk_[SITER];
    if (fits) {
        int src = t * chunkE + srow[t];
        int dst = spref[t];
        int len = hrow[t];
        for (int q = 0; q < len; q++) stage[dst + q] = srt[src + q];
        __syncthreads();
        // histogram with rank recording
#pragma unroll
        for (int q = 0; q < SITER; q++) {
            int e = t + q * 256;
            int rv = -1;
            if (e < S) rv = atomicAdd(&cnt[stage[e] >> 17], 1);
            rk_[q] = rv;
        }
    } else {
        int src = t * chunkE + srow[t];
        int len = hrow[t];
        for (int q = 0; q < len; q++) atomicAdd(&cnt[srt[src + q] >> 17], 1);
    }
    __syncthreads();
    // scan cnt[0..128) -> colb; emit ptr/dinv; exclusive bases
    if (t < WC) colb[t] = cnt[t];
    __syncthreads();
    for (int off = 1; off < WC; off <<= 1) {
        int u = 0;
        if (t >= off && t < WC) u = colb[t - off];
        __syncthreads();
        if (t >= off && t < WC) colb[t] += u;
        __syncthreads();
    }
    if (t < WC) {
        int excl = colb[t] - cnt[t];
        int c = j * WC + t;
        cexc[t] = gbase + excl;
        if (c < n) {
            ptr[c] = gbase + excl;
            dinv[c] = cnt[t] > 0 ? rsqrtf((float)cnt[t]) : 0.0f;
        }
    }
    if (j == B - 1 && t == 0) ptr[n] = E;
    __syncthreads();
    if (fits) {
        // replay from recorded ranks
#pragma unroll
        for (int q = 0; q < SITER; q++) {
            int e = t + q * 256;
            if (e < S) {
                int pk = stage[e];
                srt2[cexc[pk >> 17] + rk_[q]] = pk & 0x1FFFF;
            }
        }
    } else {
        int src = t * chunkE + srow[t];
        int len = hrow[t];
        for (int q = 0; q < len; q++) {
            int pk = srt[src + q];
            int pos = atomicAdd(&cexc[pk >> 17], 1);
            srt2[pos] = pk & 0x1FFFF;
        }
    }
}

// ---- node degree counting sort -> perm (degree-grouped gather order) ----
__global__ __launch_bounds__(1024)
void deg_hist_kernel(const int* __restrict__ ptr, int* __restrict__ dhist, int n) {
    __shared__ int h[256];
    int blk = blockIdx.x, t = threadIdx.x;
    if (t < 256) h[t] = 0;
    __syncthreads();
    int i = blk * 1024 + t;
    if (i < n) {
        int d = ptr[i + 1] - ptr[i];
        atomicAdd(&h[d < 255 ? d : 255], 1);
    }
    __syncthreads();
    if (t < 256) dhist[(size_t)blk * 256 + t] = h[t];
}

// Single block: exclusive scan over dhist in (bin, block)-major order -> dbase.
__global__ __launch_bounds__(1024)
void deg_scan_kernel(const int* __restrict__ dhist, int* __restrict__ dbase, int nb2) {
    __shared__ int s[1024];
    int t = threadIdx.x;
    int M = 256 * nb2;
    int chunk = (M + 1023) / 1024;
    int lo = t * chunk, hi = lo + chunk; if (hi > M) hi = M;
    int sum = 0;
    for (int m = lo; m < hi; m++) {
        int bin = m / nb2, blk = m - bin * nb2;
        sum += dhist[(size_t)blk * 256 + bin];
    }
    s[t] = sum;
    __syncthreads();
    for (int off = 1; off < 1024; off <<= 1) {
        int u = 0;
        if (t >= off) u = s[t - off];
        __syncthreads();
        if (t >= off) s[t] += u;
        __syncthreads();
    }
    int run = s[t] - sum;
    for (int m = lo; m < hi; m++) {
        int bin = m / nb2, blk = m - bin * nb2;
        dbase[(size_t)blk * 256 + bin] = run;
        run += dhist[(size_t)blk * 256 + bin];
    }
}

__global__ __launch_bounds__(1024)
void deg_scatter_kernel(const int* __restrict__ ptr, const int* __restrict__ dbase,
                        int* __restrict__ perm, int n) {
    __shared__ int cur[256];
    int blk = blockIdx.x, t = threadIdx.x;
    if (t < 256) cur[t] = dbase[(size_t)blk * 256 + t];
    __syncthreads();
    int i = blk * 1024 + t;
    if (i < n) {
        int d = ptr[i + 1] - ptr[i];
        int pos = atomicAdd(&cur[d < 255 ? d : 255], 1);
        perm[pos] = i;
    }
}

// p row = 8 uint32 (16 bf16) = 32 B.
template <int FI>
__global__ void proj_kernel(const float* __restrict__ hin, const float* __restrict__ W,
                            const float* __restrict__ dinv, unsigned* __restrict__ p, int n) {
    __shared__ float sW[FI * 16];
    for (int t = threadIdx.x; t < FI * 16; t += blockDim.x) sW[t] = W[t];
    __syncthreads();
    int i = blockIdx.x * blockDim.x + threadIdx.x;
    if (i >= n) return;
    float hi[FI];
    const float4* hr = (const float4*)(hin + (size_t)i * FI);
#pragma unroll
    for (int k = 0; k < FI / 4; k++) {
        float4 v = hr[k];
        hi[4 * k] = v.x; hi[4 * k + 1] = v.y; hi[4 * k + 2] = v.z; hi[4 * k + 3] = v.w;
    }
    float di = dinv[i];
    float outv[16];
#pragma unroll
    for (int f = 0; f < 16; f++) {
        float s = 0.0f;
#pragma unroll
        for (int k = 0; k < FI; k++) s += hi[k] * sW[k * 16 + f];
        outv[f] = s * di;
    }
    uint4 u0, u1;
    u0.x = bf16rte(outv[0])  | (bf16rte(outv[1])  << 16);
    u0.y = bf16rte(outv[2])  | (bf16rte(outv[3])  << 16);
    u0.z = bf16rte(outv[4])  | (bf16rte(outv[5])  << 16);
    u0.w = bf16rte(outv[6])  | (bf16rte(outv[7])  << 16);
    u1.x = bf16rte(outv[8])  | (bf16rte(outv[9])  << 16);
    u1.y = bf16rte(outv[10]) | (bf16rte(outv[11]) << 16);
    u1.z = bf16rte(outv[12]) | (bf16rte(outv[13]) << 16);
    u1.w = bf16rte(outv[14]) | (bf16rte(outv[15]) << 16);
    uint4* pr = (uint4*)(p + (size_t)i * 8);
    pr[0] = u0;
    pr[1] = u1;
}

// 4 lanes per node, nodes taken in degree-grouped perm order (wave = 16
// similar-degree nodes -> minimal trip-count divergence). hb = feature half,
// sh = edge half; predicated unroll-8; shfl_xor merge; fused finish on sh==0.
// hin/out may alias (layer 2): a node's h row is read only by its own lanes and
// all reads precede the stores in program order (perm is a bijection).
template <int FI>
__global__ __launch_bounds__(256, 4)
void gather_finish_kernel(const int* __restrict__ ptr, const int* __restrict__ srt2,
                          const uintv4* __restrict__ p, const float* hin,
                          const float* __restrict__ V, const float* __restrict__ b,
                          const float* __restrict__ dinv, const int* __restrict__ perm,
                          float* out, int n) {
    __shared__ float sV[FI * 16];
    __shared__ float sb[16];
    for (int t = threadIdx.x; t < FI * 16; t += blockDim.x) sV[t] = V[t];
    if (threadIdx.x < 16) sb[threadIdx.x] = b[threadIdx.x];
    __syncthreads();
    int gg = blockIdx.x * (blockDim.x >> 2) + (threadIdx.x >> 2);
    int hb = threadIdx.x & 1;
    int sh = (threadIdx.x >> 1) & 1;
    if (gg >= n) return;
    int g = perm[gg];
    int s0 = ptr[g], s1 = ptr[g + 1];
    int mid = (s0 + s1) >> 1;
    int e0 = sh ? mid : s0;
    int e1 = sh ? s1 : mid;
    const uintv4* pb = p + hb;          // lane's half: p[(size_t)r*2 + hb]
    float a0 = 0, a1 = 0, a2 = 0, a3 = 0, a4 = 0, a5 = 0, a6 = 0, a7 = 0;
    for (int e = e0; e < e1; e += 8) {
        int r[8];
#pragma unroll
        for (int q = 0; q < 8; q++) {
            int idx = e + q;
            r[q] = __builtin_nontemporal_load(srt2 + (idx < e1 ? idx : e1 - 1));
        }
        uintv4 u[8];
#pragma unroll
        for (int q = 0; q < 8; q++) u[q] = pb[(size_t)r[q] * 2];
#pragma unroll
        for (int q = 0; q < 8; q++) {
            if (e + q >= e1) u[q] = (uintv4)0;   // cndmask-zero: bf16 0 -> 0.0f
            a0 += __uint_as_float(u[q][0] << 16);
            a1 += __uint_as_float(u[q][0] & 0xFFFF0000u);
            a2 += __uint_as_float(u[q][1] << 16);
            a3 += __uint_as_float(u[q][1] & 0xFFFF0000u);
            a4 += __uint_as_float(u[q][2] << 16);
            a5 += __uint_as_float(u[q][2] & 0xFFFF0000u);
            a6 += __uint_as_float(u[q][3] << 16);
            a7 += __uint_as_float(u[q][3] & 0xFFFF0000u);
        }
    }
    // merge edge halves (lane ^ 2 is the other sh, same hb, same node)
    a0 += __shfl_xor(a0, 2);
    a1 += __shfl_xor(a1, 2);
    a2 += __shfl_xor(a2, 2);
    a3 += __shfl_xor(a3, 2);
    a4 += __shfl_xor(a4, 2);
    a5 += __shfl_xor(a5, 2);
    a6 += __shfl_xor(a6, 2);
    a7 += __shfl_xor(a7, 2);
    if (sh != 0) return;
    // fused finish: h@V + b + dinv*agg, relu (features f0..f0+7)
    int f0 = hb * 8;
    float hi[FI];
    const float4* h4 = (const float4*)(hin + (size_t)g * FI);
#pragma unroll
    for (int k = 0; k < FI / 4; k++) {
        float4 v = h4[k];
        hi[4 * k] = v.x; hi[4 * k + 1] = v.y; hi[4 * k + 2] = v.z; hi[4 * k + 3] = v.w;
    }
    float hv[8] = {0, 0, 0, 0, 0, 0, 0, 0};
#pragma unroll
    for (int k = 0; k < FI; k++) {
        float hk = hi[k];
#pragma unroll
        for (int q = 0; q < 8; q++) hv[q] += hk * sV[k * 16 + f0 + q];
    }
    float di = dinv[g];
    float rr[8] = {a0, a1, a2, a3, a4, a5, a6, a7};
#pragma unroll
    for (int q = 0; q < 8; q++) {
        float r_ = sb[f0 + q] + di * rr[q] + hv[q];
        rr[q] = r_ > 0.0f ? r_ : 0.0f;
    }
    float4* o4 = (float4*)(out + (size_t)g * 16 + f0);
    o4[0] = make_float4(rr[0], rr[1], rr[2], rr[3]);
    o4[1] = make_float4(rr[4], rr[5], rr[6], rr[7]);
}

extern "C" void kernel_launch(void* const* d_in, const int* in_sizes, int n_in,
                              void* d_out, int out_size, void* d_ws, size_t ws_size,
                              hipStream_t stream) {
    const float* x  = (const float*)d_in[0];
    const int*   ei = (const int*)d_in[1];
    const float* W1 = (const float*)d_in[2];
    const float* V1 = (const float*)d_in[3];
    const float* b1 = (const float*)d_in[4];
    const float* W2 = (const float*)d_in[5];
    const float* V2 = (const float*)d_in[6];
    const float* b2 = (const float*)d_in[7];

    const int n = in_sizes[0] / 8;       // 100000 nodes
    const int E = in_sizes[1] / 2;       // 3200000 edges
    const int* row = ei;                 // edge_index[0]
    const int* col = ei + E;             // edge_index[1]

    const int B = (n + WC - 1) / WC;     // 782 buckets
    const int chunkE = (E + NBC - 1) / NBC;  // 12500 (CITER*1024 >= chunkE)
    const int nb2 = (n + 1023) / 1024;   // 98 node blocks

    auto align = [](size_t v) { return (v + 255) / 256 * 256; };
    char* ws = (char*)d_ws;
    size_t off = 0;
    float* dinv  = (float*)(ws + off); off += align((size_t)n * 4);
    int*   ptr   = (int*)(ws + off);   off += align((size_t)(n + 1) * 4);
    int*   histg = (int*)(ws + off);   off += align((size_t)NBC * B * 4);
    int*   segst = (int*)(ws + off);   off += align((size_t)NBC * B * 4);
    int*   part  = (int*)(ws + off);   off += align((size_t)8 * B * 4);
    int*   bbase = (int*)(ws + off);   off += align((size_t)B * 4);
    int*   dhist = (int*)(ws + off);   off += align((size_t)nb2 * 256 * 4);
    int*   dbase = (int*)(ws + off);   off += align((size_t)nb2 * 256 * 4);
    int*   perm  = (int*)(ws + off);   off += align((size_t)n * 4);
    // srt is dead after bucket_sort; proj writes packed p over the same region.
    int*      srt = (int*)(ws + off);
    unsigned* p   = (unsigned*)(ws + off); off += align((size_t)E * 4);  // E*4 >= n*8*4
    int*      srt2 = (int*)(ws + off);     off += align((size_t)E * 4);
    float* out = (float*)d_out;
    // ~29 MB total

    const int bs = 256;
    const int gbN = (n + bs - 1) / bs;
    const int gbG = (n * 4 + bs - 1) / bs;   // gather: 4 lanes per node

    // CSR build (no global atomics; single-writer L2-resident write windows)
    chunk_sort<<<NBC, 1024, 0, stream>>>(row, col, srt, histg, segst, E, B, chunkE);
    tot8_kernel<<<(8 * B + bs - 1) / bs, bs, 0, stream>>>(histg, part, B);
    scan1024_kernel<<<1, 1024, 0, stream>>>(part, bbase, B);
    bucket_sort<<<B, bs, 0, stream>>>(srt, histg, segst, bbase, ptr, srt2, dinv, E, n, B, chunkE);

    // degree-grouped node order
    deg_hist_kernel<<<nb2, 1024, 0, stream>>>(ptr, dhist, n);
    deg_scan_kernel<<<1, 1024, 0, stream>>>(dhist, dbase, nb2);
    deg_scatter_kernel<<<nb2, 1024, 0, stream>>>(ptr, dbase, perm, n);

    // Layer 1 (FI=8): x -> d_out   (proj overwrites srt region with p — srt is dead)
    proj_kernel<8><<<gbN, bs, 0, stream>>>(x, W1, dinv, p, n);
    gather_finish_kernel<8><<<gbG, bs, 0, stream>>>(ptr, srt2, (const uintv4*)p, x, V1, b1, dinv, perm, out, n);

    // Layer 2 (FI=16): d_out -> d_out
    proj_kernel<16><<<gbN, bs, 0, stream>>>(out, W2, dinv, p, n);
    gather_finish_kernel<16><<<gbG, bs, 0, stream>>>(ptr, srt2, (const uintv4*)p, out, V2, b2, dinv, perm, out, n);
}

// Round 15
// 149.081 us; speedup vs baseline: 1.5199x; 1.5199x over previous
//
#include <hip/hip_runtime.h>

// ARMA GNN (T=1,K=1) x2 layers on MI355X — chunk-major partition (one-pass
// rank-replay sorts) + natural-order bf16-packed 4-lane gather.
//
// Round-14 lesson: degree-grouped perm REGRESSED gather (35->58us, FETCH
// 38->53MB): wave-contiguous CSR ranges are load-bearing for srt2 streaming;
// balance gain < coalescing loss. Revert to natural node order. Keep the
// one-pass rank-recording sorts (round 13): LDS atomicAdd returns the
// within-segment rank during the histogram pass; replay from static-indexed
// register arrays -> no second global read of row/col, no second LDS-atomic
// pass.
//
// Pipeline (built once, reused by both layers):
//   CS chunk_sort:  block i (1024 thr) one-pass counting-sorts its 12500-edge
//                   chunk by bucket; srt CHUNK-MAJOR + histg/segst tables.
//   T  tot8 / S scan1024: bucket totals -> bucket_base
//   BS bucket_sort: per bucket: segments -> LDS stage, rank-recorded col sort
//                   -> ptr/dinv/srt2 (CSR).
// Per layer:
//   proj:   p[i] = pack_bf16x2((h[i] @ W) * dinv[i])   (p overlays dead srt)
//   gather: 4 lanes/node (hb=feat-half, sh=edge-half), natural order,
//           predicated unroll-8, fp32 accum, shfl_xor combine,
//           fused h@V+b+relu, float4 stores.

#define WC 128          // bucket width (cols)
#define LG2WC 7
#define MAXB 1024       // padded bucket count (supports n up to 131072)
#define NBC 256         // partition chunks
#define SCAP 8192       // bucket_sort LDS stage capacity
#define CITER 13        // ceil(chunkE/1024), chunkE = 12500
#define SITER 32        // SCAP/256

typedef unsigned uintv4 __attribute__((ext_vector_type(4)));

__device__ inline unsigned bf16rte(float x) {
    unsigned u = __float_as_uint(x);
    return (u + 0x7FFFu + ((u >> 16) & 1u)) >> 16;
}

// Block i (1024 threads): ONE-PASS counting sort of its chunk by bucket.
__global__ __launch_bounds__(1024)
void chunk_sort(const int* __restrict__ row, const int* __restrict__ col,
                int* __restrict__ srt, int* __restrict__ histg,
                int* __restrict__ segst, int E, int B, int chunkE) {
    __shared__ int hist[MAXB];
    __shared__ int cur[MAXB];
    __shared__ int tsum[MAXB];
    int i = blockIdx.x, t = threadIdx.x;
    hist[t] = 0;
    __syncthreads();
    int lo = i * chunkE, hi = lo + chunkE; if (hi > E) hi = E;
    int pk_[CITER];
    unsigned br_[CITER];
#pragma unroll
    for (int q = 0; q < CITER; q++) {
        int e = lo + t + q * 1024;
        int pkv = 0; unsigned brv = 0xFFFFFFFFu;
        if (e < hi) {
            int c = col[e];
            int r = row[e];
            int bkt = c >> LG2WC;
            int rank = atomicAdd(&hist[bkt], 1);       // LDS; rank within (chunk,bucket)
            pkv = ((c & (WC - 1)) << 17) | r;          // row<2^17, lcol bits 17..23
            brv = (unsigned)bkt | ((unsigned)rank << 10);
        }
        pk_[q] = pkv; br_[q] = brv;
    }
    __syncthreads();
    // exclusive scan hist[0..1024) -> cur (1 elem/thread Hillis-Steele)
    int v = hist[t];
    tsum[t] = v;
    __syncthreads();
    for (int off = 1; off < 1024; off <<= 1) {
        int u = 0;
        if (t >= off) u = tsum[t - off];
        __syncthreads();
        if (t >= off) tsum[t] += u;
        __syncthreads();
    }
    cur[t] = tsum[t] - v;
    __syncthreads();
    // write tables (chunk-major, coalesced)
    if (t < B) {
        histg[(size_t)i * B + t] = hist[t];
        segst[(size_t)i * B + t] = cur[t];
    }
    // replay: position = window base + bucket base + recorded rank
#pragma unroll
    for (int q = 0; q < CITER; q++) {
        if (br_[q] != 0xFFFFFFFFu) {
            int bkt = br_[q] & 1023;
            int rank = (int)(br_[q] >> 10);
            srt[lo + cur[bkt] + rank] = pk_[q];
        }
    }
}

// part[k*B+j] = sum_{i in slice k} histg[i*B+j]; 8 slices of 32 chunks.
__global__ void tot8_kernel(const int* __restrict__ histg, int* __restrict__ part, int B) {
    int idx = blockIdx.x * blockDim.x + threadIdx.x;
    if (idx >= 8 * B) return;
    int k = idx / B, j = idx - k * B;
    int s = 0;
    for (int i = k * 32; i < k * 32 + 32; i++) s += histg[(size_t)i * B + j];
    part[(size_t)k * B + j] = s;
}

__global__ void scan1024_kernel(const int* __restrict__ part, int* __restrict__ base, int B) {
    __shared__ int s[1024];
    int t = threadIdx.x;
    int v = 0;
    if (t < B) {
#pragma unroll
        for (int k = 0; k < 8; k++) v += part[(size_t)k * B + t];
    }
    s[t] = v;
    __syncthreads();
    for (int off = 1; off < 1024; off <<= 1) {
        int u = 0;
        if (t >= off) u = s[t - off];
        __syncthreads();
        if (t >= off) s[t] += u;
        __syncthreads();
    }
    if (t < B) base[t] = s[t] - v;  // exclusive
}

// Per bucket: segments -> LDS stage; one-pass rank-recorded col sort -> srt2.
__global__ void bucket_sort(const int* __restrict__ srt, const int* __restrict__ histg,
                            const int* __restrict__ segst, const int* __restrict__ bbase,
                            int* __restrict__ ptr, int* __restrict__ srt2,
                            float* __restrict__ dinv, int E, int n, int B, int chunkE) {
    __shared__ int hrow[NBC];
    __shared__ int srow[NBC];
    __shared__ int spref[NBC];
    __shared__ int stage[SCAP];
    __shared__ int tsum[256];
    __shared__ int cnt[WC], colb[WC], cexc[WC];
    __shared__ int Ssh;
    int j = blockIdx.x, t = threadIdx.x;
    hrow[t] = histg[(size_t)t * B + j];
    srow[t] = segst[(size_t)t * B + j];
    if (t < WC) cnt[t] = 0;
    __syncthreads();
    // exclusive scan hrow[0..256) -> spref
    int v = hrow[t];
    tsum[t] = v;
    __syncthreads();
    for (int off = 1; off < 256; off <<= 1) {
        int u = 0;
        if (t >= off) u = tsum[t - off];
        __syncthreads();
        if (t >= off) tsum[t] += u;
        __syncthreads();
    }
    spref[t] = tsum[t] - v;
    if (t == 255) Ssh = tsum[255];
    __syncthreads();
    int S = Ssh;                 // bucket size (block-uniform)
    int gbase = bbase[j];
    bool fits = (S <= SCAP);     // uniform branch (S ~ Po(4096), SCAP=8192)
    int rk_[SITER];
    if (fits) {
        int src = t * chunkE + srow[t];
        int dst = spref[t];
        int len = hrow[t];
        for (int q = 0; q < len; q++) stage[dst + q] = srt[src + q];
        __syncthreads();
        // histogram with rank recording
#pragma unroll
        for (int q = 0; q < SITER; q++) {
            int e = t + q * 256;
            int rv = -1;
            if (e < S) rv = atomicAdd(&cnt[stage[e] >> 17], 1);
            rk_[q] = rv;
        }
    } else {
        int src = t * chunkE + srow[t];
        int len = hrow[t];
        for (int q = 0; q < len; q++) atomicAdd(&cnt[srt[src + q] >> 17], 1);
    }
    __syncthreads();
    // scan cnt[0..128) -> colb; emit ptr/dinv; exclusive bases
    if (t < WC) colb[t] = cnt[t];
    __syncthreads();
    for (int off = 1; off < WC; off <<= 1) {
        int u = 0;
        if (t >= off && t < WC) u = colb[t - off];
        __syncthreads();
        if (t >= off && t < WC) colb[t] += u;
        __syncthreads();
    }
    if (t < WC) {
        int excl = colb[t] - cnt[t];
        int c = j * WC + t;
        cexc[t] = gbase + excl;
        if (c < n) {
            ptr[c] = gbase + excl;
            dinv[c] = cnt[t] > 0 ? rsqrtf((float)cnt[t]) : 0.0f;
        }
    }
    if (j == B - 1 && t == 0) ptr[n] = E;
    __syncthreads();
    if (fits) {
        // replay from recorded ranks
#pragma unroll
        for (int q = 0; q < SITER; q++) {
            int e = t + q * 256;
            if (e < S) {
                int pk = stage[e];
                srt2[cexc[pk >> 17] + rk_[q]] = pk & 0x1FFFF;
            }
        }
    } else {
        int src = t * chunkE + srow[t];
        int len = hrow[t];
        for (int q = 0; q < len; q++) {
            int pk = srt[src + q];
            int pos = atomicAdd(&cexc[pk >> 17], 1);
            srt2[pos] = pk & 0x1FFFF;
        }
    }
}

// p row = 8 uint32 (16 bf16) = 32 B.
template <int FI>
__global__ void proj_kernel(const float* __restrict__ hin, const float* __restrict__ W,
                            const float* __restrict__ dinv, unsigned* __restrict__ p, int n) {
    __shared__ float sW[FI * 16];
    for (int t = threadIdx.x; t < FI * 16; t += blockDim.x) sW[t] = W[t];
    __syncthreads();
    int i = blockIdx.x * blockDim.x + threadIdx.x;
    if (i >= n) return;
    float hi[FI];
    const float4* hr = (const float4*)(hin + (size_t)i * FI);
#pragma unroll
    for (int k = 0; k < FI / 4; k++) {
        float4 v = hr[k];
        hi[4 * k] = v.x; hi[4 * k + 1] = v.y; hi[4 * k + 2] = v.z; hi[4 * k + 3] = v.w;
    }
    float di = dinv[i];
    float outv[16];
#pragma unroll
    for (int f = 0; f < 16; f++) {
        float s = 0.0f;
#pragma unroll
        for (int k = 0; k < FI; k++) s += hi[k] * sW[k * 16 + f];
        outv[f] = s * di;
    }
    uint4 u0, u1;
    u0.x = bf16rte(outv[0])  | (bf16rte(outv[1])  << 16);
    u0.y = bf16rte(outv[2])  | (bf16rte(outv[3])  << 16);
    u0.z = bf16rte(outv[4])  | (bf16rte(outv[5])  << 16);
    u0.w = bf16rte(outv[6])  | (bf16rte(outv[7])  << 16);
    u1.x = bf16rte(outv[8])  | (bf16rte(outv[9])  << 16);
    u1.y = bf16rte(outv[10]) | (bf16rte(outv[11]) << 16);
    u1.z = bf16rte(outv[12]) | (bf16rte(outv[13]) << 16);
    u1.w = bf16rte(outv[14]) | (bf16rte(outv[15]) << 16);
    uint4* pr = (uint4*)(p + (size_t)i * 8);
    pr[0] = u0;
    pr[1] = u1;
}

// 4 lanes per node (natural order): hb = feature half (16B of 32B row), sh =
// edge half. Predicated unroll-8 (no serial tail); shfl_xor merge; fused
// finish on sh==0. hin/out may alias (layer 2): a node's h row is read only by
// its own lanes and all reads precede the stores in wave program order.
template <int FI>
__global__ __launch_bounds__(256, 4)
void gather_finish_kernel(const int* __restrict__ ptr, const int* __restrict__ srt2,
                          const uintv4* __restrict__ p, const float* hin,
                          const float* __restrict__ V, const float* __restrict__ b,
                          const float* __restrict__ dinv, float* out, int n) {
    __shared__ float sV[FI * 16];
    __shared__ float sb[16];
    for (int t = threadIdx.x; t < FI * 16; t += blockDim.x) sV[t] = V[t];
    if (threadIdx.x < 16) sb[threadIdx.x] = b[threadIdx.x];
    __syncthreads();
    int g = blockIdx.x * (blockDim.x >> 2) + (threadIdx.x >> 2);
    int hb = threadIdx.x & 1;
    int sh = (threadIdx.x >> 1) & 1;
    if (g >= n) return;
    int s0 = ptr[g], s1 = ptr[g + 1];
    int mid = (s0 + s1) >> 1;
    int e0 = sh ? mid : s0;
    int e1 = sh ? s1 : mid;
    const uintv4* pb = p + hb;          // lane's half: p[(size_t)r*2 + hb]
    float a0 = 0, a1 = 0, a2 = 0, a3 = 0, a4 = 0, a5 = 0, a6 = 0, a7 = 0;
    for (int e = e0; e < e1; e += 8) {
        int r[8];
#pragma unroll
        for (int q = 0; q < 8; q++) {
            int idx = e + q;
            r[q] = __builtin_nontemporal_load(srt2 + (idx < e1 ? idx : e1 - 1));
        }
        uintv4 u[8];
#pragma unroll
        for (int q = 0; q < 8; q++) u[q] = pb[(size_t)r[q] * 2];
#pragma unroll
        for (int q = 0; q < 8; q++) {
            if (e + q >= e1) u[q] = (uintv4)0;   // cndmask-zero: bf16 0 -> 0.0f
            a0 += __uint_as_float(u[q][0] << 16);
            a1 += __uint_as_float(u[q][0] & 0xFFFF0000u);
            a2 += __uint_as_float(u[q][1] << 16);
            a3 += __uint_as_float(u[q][1] & 0xFFFF0000u);
            a4 += __uint_as_float(u[q][2] << 16);
            a5 += __uint_as_float(u[q][2] & 0xFFFF0000u);
            a6 += __uint_as_float(u[q][3] << 16);
            a7 += __uint_as_float(u[q][3] & 0xFFFF0000u);
        }
    }
    // merge edge halves (lane ^ 2 is the other sh, same hb, same node)
    a0 += __shfl_xor(a0, 2);
    a1 += __shfl_xor(a1, 2);
    a2 += __shfl_xor(a2, 2);
    a3 += __shfl_xor(a3, 2);
    a4 += __shfl_xor(a4, 2);
    a5 += __shfl_xor(a5, 2);
    a6 += __shfl_xor(a6, 2);
    a7 += __shfl_xor(a7, 2);
    if (sh != 0) return;
    // fused finish: h@V + b + dinv*agg, relu (features f0..f0+7)
    int f0 = hb * 8;
    float hi[FI];
    const float4* h4 = (const float4*)(hin + (size_t)g * FI);
#pragma unroll
    for (int k = 0; k < FI / 4; k++) {
        float4 v = h4[k];
        hi[4 * k] = v.x; hi[4 * k + 1] = v.y; hi[4 * k + 2] = v.z; hi[4 * k + 3] = v.w;
    }
    float hv[8] = {0, 0, 0, 0, 0, 0, 0, 0};
#pragma unroll
    for (int k = 0; k < FI; k++) {
        float hk = hi[k];
#pragma unroll
        for (int q = 0; q < 8; q++) hv[q] += hk * sV[k * 16 + f0 + q];
    }
    float di = dinv[g];
    float rr[8] = {a0, a1, a2, a3, a4, a5, a6, a7};
#pragma unroll
    for (int q = 0; q < 8; q++) {
        float r_ = sb[f0 + q] + di * rr[q] + hv[q];
        rr[q] = r_ > 0.0f ? r_ : 0.0f;
    }
    float4* o4 = (float4*)(out + (size_t)g * 16 + f0);
    o4[0] = make_float4(rr[0], rr[1], rr[2], rr[3]);
    o4[1] = make_float4(rr[4], rr[5], rr[6], rr[7]);
}

extern "C" void kernel_launch(void* const* d_in, const int* in_sizes, int n_in,
                              void* d_out, int out_size, void* d_ws, size_t ws_size,
                              hipStream_t stream) {
    const float* x  = (const float*)d_in[0];
    const int*   ei = (const int*)d_in[1];
    const float* W1 = (const float*)d_in[2];
    const float* V1 = (const float*)d_in[3];
    const float* b1 = (const float*)d_in[4];
    const float* W2 = (const float*)d_in[5];
    const float* V2 = (const float*)d_in[6];
    const float* b2 = (const float*)d_in[7];

    const int n = in_sizes[0] / 8;       // 100000 nodes
    const int E = in_sizes[1] / 2;       // 3200000 edges
    const int* row = ei;                 // edge_index[0]
    const int* col = ei + E;             // edge_index[1]

    const int B = (n + WC - 1) / WC;     // 782 buckets
    const int chunkE = (E + NBC - 1) / NBC;  // 12500 (CITER*1024 >= chunkE)

    auto align = [](size_t v) { return (v + 255) / 256 * 256; };
    char* ws = (char*)d_ws;
    size_t off = 0;
    float* dinv  = (float*)(ws + off); off += align((size_t)n * 4);
    int*   ptr   = (int*)(ws + off);   off += align((size_t)(n + 1) * 4);
    int*   histg = (int*)(ws + off);   off += align((size_t)NBC * B * 4);
    int*   segst = (int*)(ws + off);   off += align((size_t)NBC * B * 4);
    int*   part  = (int*)(ws + off);   off += align((size_t)8 * B * 4);
    int*   bbase = (int*)(ws + off);   off += align((size_t)B * 4);
    // srt is dead after bucket_sort; proj writes packed p over the same region.
    int*      srt = (int*)(ws + off);
    unsigned* p   = (unsigned*)(ws + off); off += align((size_t)E * 4);  // E*4 >= n*8*4
    int*      srt2 = (int*)(ws + off);     off += align((size_t)E * 4);
    float* out = (float*)d_out;
    // ~28 MB total

    const int bs = 256;
    const int gbN = (n + bs - 1) / bs;
    const int gbG = (n * 4 + bs - 1) / bs;   // gather: 4 lanes per node

    // CSR build (no global atomics; single-writer L2-resident write windows)
    chunk_sort<<<NBC, 1024, 0, stream>>>(row, col, srt, histg, segst, E, B, chunkE);
    tot8_kernel<<<(8 * B + bs - 1) / bs, bs, 0, stream>>>(histg, part, B);
    scan1024_kernel<<<1, 1024, 0, stream>>>(part, bbase, B);
    bucket_sort<<<B, bs, 0, stream>>>(srt, histg, segst, bbase, ptr, srt2, dinv, E, n, B, chunkE);

    // Layer 1 (FI=8): x -> d_out   (proj overwrites srt region with p — srt is dead)
    proj_kernel<8><<<gbN, bs, 0, stream>>>(x, W1, dinv, p, n);
    gather_finish_kernel<8><<<gbG, bs, 0, stream>>>(ptr, srt2, (const uintv4*)p, x, V1, b1, dinv, out, n);

    // Layer 2 (FI=16): d_out -> d_out
    proj_kernel<16><<<gbN, bs, 0, stream>>>(out, W2, dinv, p, n);
    gather_finish_kernel<16><<<gbG, bs, 0, stream>>>(ptr, srt2, (const uintv4*)p, out, V2, b2, dinv, out, n);
}

// Round 16
// 140.527 us; speedup vs baseline: 1.6124x; 1.0609x over previous
//
#include <hip/hip_runtime.h>

// ARMA GNN (T=1,K=1) x2 layers on MI355X — chunk-major partition (one-pass
// rank-replay sorts) + natural-order bf16-packed 4-lane gather with int4
// index loads.
//
// Round-15 state: 149us, flat profile (gather 41+35, chunk 30, bucket 25).
// Last unreduced gather component: srt2 index loads were 8 scalar dwords per
// unroll block (half of all TA slots). Fix: 4-aligned int4 srt2 loads from
// e0&~3 with predication extended to mask [e0,e1) bounds (neighbor-col
// entries are valid rows; contribution zeroed; &0x1FFFF keeps over-reads
// in-bounds). 4x fewer index-load instructions.
//
// Pipeline (built once, reused by both layers):
//   CS chunk_sort:  block i (1024 thr) one-pass counting-sorts its 12500-edge
//                   chunk by bucket; srt CHUNK-MAJOR + histg/segst tables.
//   T  tot8 / S scan1024: bucket totals -> bucket_base
//   BS bucket_sort: per bucket: segments -> LDS stage, rank-recorded col sort
//                   -> ptr/dinv/srt2 (CSR).
// Per layer:
//   proj:   p[i] = pack_bf16x2((h[i] @ W) * dinv[i])   (p overlays dead srt)
//   gather: 4 lanes/node (hb=feat-half, sh=edge-half), int4 index loads,
//           predicated unroll-8, fp32 accum, shfl_xor combine,
//           fused h@V+b+relu, float4 stores.

#define WC 128          // bucket width (cols)
#define LG2WC 7
#define MAXB 1024       // padded bucket count (supports n up to 131072)
#define NBC 256         // partition chunks
#define SCAP 8192       // bucket_sort LDS stage capacity
#define CITER 13        // ceil(chunkE/1024), chunkE = 12500
#define SITER 32        // SCAP/256

typedef unsigned uintv4 __attribute__((ext_vector_type(4)));
typedef int intv4 __attribute__((ext_vector_type(4)));

__device__ inline unsigned bf16rte(float x) {
    unsigned u = __float_as_uint(x);
    return (u + 0x7FFFu + ((u >> 16) & 1u)) >> 16;
}

// Block i (1024 threads): ONE-PASS counting sort of its chunk by bucket.
__global__ __launch_bounds__(1024)
void chunk_sort(const int* __restrict__ row, const int* __restrict__ col,
                int* __restrict__ srt, int* __restrict__ histg,
                int* __restrict__ segst, int E, int B, int chunkE) {
    __shared__ int hist[MAXB];
    __shared__ int cur[MAXB];
    __shared__ int tsum[MAXB];
    int i = blockIdx.x, t = threadIdx.x;
    hist[t] = 0;
    __syncthreads();
    int lo = i * chunkE, hi = lo + chunkE; if (hi > E) hi = E;
    int pk_[CITER];
    unsigned br_[CITER];
#pragma unroll
    for (int q = 0; q < CITER; q++) {
        int e = lo + t + q * 1024;
        int pkv = 0; unsigned brv = 0xFFFFFFFFu;
        if (e < hi) {
            int c = col[e];
            int r = row[e];
            int bkt = c >> LG2WC;
            int rank = atomicAdd(&hist[bkt], 1);       // LDS; rank within (chunk,bucket)
            pkv = ((c & (WC - 1)) << 17) | r;          // row<2^17, lcol bits 17..23
            brv = (unsigned)bkt | ((unsigned)rank << 10);
        }
        pk_[q] = pkv; br_[q] = brv;
    }
    __syncthreads();
    // exclusive scan hist[0..1024) -> cur (1 elem/thread Hillis-Steele)
    int v = hist[t];
    tsum[t] = v;
    __syncthreads();
    for (int off = 1; off < 1024; off <<= 1) {
        int u = 0;
        if (t >= off) u = tsum[t - off];
        __syncthreads();
        if (t >= off) tsum[t] += u;
        __syncthreads();
    }
    cur[t] = tsum[t] - v;
    __syncthreads();
    // write tables (chunk-major, coalesced)
    if (t < B) {
        histg[(size_t)i * B + t] = hist[t];
        segst[(size_t)i * B + t] = cur[t];
    }
    // replay: position = window base + bucket base + recorded rank
#pragma unroll
    for (int q = 0; q < CITER; q++) {
        if (br_[q] != 0xFFFFFFFFu) {
            int bkt = br_[q] & 1023;
            int rank = (int)(br_[q] >> 10);
            srt[lo + cur[bkt] + rank] = pk_[q];
        }
    }
}

// part[k*B+j] = sum_{i in slice k} histg[i*B+j]; 8 slices of 32 chunks.
__global__ void tot8_kernel(const int* __restrict__ histg, int* __restrict__ part, int B) {
    int idx = blockIdx.x * blockDim.x + threadIdx.x;
    if (idx >= 8 * B) return;
    int k = idx / B, j = idx - k * B;
    int s = 0;
    for (int i = k * 32; i < k * 32 + 32; i++) s += histg[(size_t)i * B + j];
    part[(size_t)k * B + j] = s;
}

__global__ void scan1024_kernel(const int* __restrict__ part, int* __restrict__ base, int B) {
    __shared__ int s[1024];
    int t = threadIdx.x;
    int v = 0;
    if (t < B) {
#pragma unroll
        for (int k = 0; k < 8; k++) v += part[(size_t)k * B + t];
    }
    s[t] = v;
    __syncthreads();
    for (int off = 1; off < 1024; off <<= 1) {
        int u = 0;
        if (t >= off) u = s[t - off];
        __syncthreads();
        if (t >= off) s[t] += u;
        __syncthreads();
    }
    if (t < B) base[t] = s[t] - v;  // exclusive
}

// Per bucket: segments -> LDS stage; one-pass rank-recorded col sort -> srt2.
__global__ void bucket_sort(const int* __restrict__ srt, const int* __restrict__ histg,
                            const int* __restrict__ segst, const int* __restrict__ bbase,
                            int* __restrict__ ptr, int* __restrict__ srt2,
                            float* __restrict__ dinv, int E, int n, int B, int chunkE) {
    __shared__ int hrow[NBC];
    __shared__ int srow[NBC];
    __shared__ int spref[NBC];
    __shared__ int stage[SCAP];
    __shared__ int tsum[256];
    __shared__ int cnt[WC], colb[WC], cexc[WC];
    __shared__ int Ssh;
    int j = blockIdx.x, t = threadIdx.x;
    hrow[t] = histg[(size_t)t * B + j];
    srow[t] = segst[(size_t)t * B + j];
    if (t < WC) cnt[t] = 0;
    __syncthreads();
    // exclusive scan hrow[0..256) -> spref
    int v = hrow[t];
    tsum[t] = v;
    __syncthreads();
    for (int off = 1; off < 256; off <<= 1) {
        int u = 0;
        if (t >= off) u = tsum[t - off];
        __syncthreads();
        if (t >= off) tsum[t] += u;
        __syncthreads();
    }
    spref[t] = tsum[t] - v;
    if (t == 255) Ssh = tsum[255];
    __syncthreads();
    int S = Ssh;                 // bucket size (block-uniform)
    int gbase = bbase[j];
    bool fits = (S <= SCAP);     // uniform branch (S ~ Po(4096), SCAP=8192)
    int rk_[SITER];
    if (fits) {
        int src = t * chunkE + srow[t];
        int dst = spref[t];
        int len = hrow[t];
        for (int q = 0; q < len; q++) stage[dst + q] = srt[src + q];
        __syncthreads();
        // histogram with rank recording
#pragma unroll
        for (int q = 0; q < SITER; q++) {
            int e = t + q * 256;
            int rv = -1;
            if (e < S) rv = atomicAdd(&cnt[stage[e] >> 17], 1);
            rk_[q] = rv;
        }
    } else {
        int src = t * chunkE + srow[t];
        int len = hrow[t];
        for (int q = 0; q < len; q++) atomicAdd(&cnt[srt[src + q] >> 17], 1);
    }
    __syncthreads();
    // scan cnt[0..128) -> colb; emit ptr/dinv; exclusive bases
    if (t < WC) colb[t] = cnt[t];
    __syncthreads();
    for (int off = 1; off < WC; off <<= 1) {
        int u = 0;
        if (t >= off && t < WC) u = colb[t - off];
        __syncthreads();
        if (t >= off && t < WC) colb[t] += u;
        __syncthreads();
    }
    if (t < WC) {
        int excl = colb[t] - cnt[t];
        int c = j * WC + t;
        cexc[t] = gbase + excl;
        if (c < n) {
            ptr[c] = gbase + excl;
            dinv[c] = cnt[t] > 0 ? rsqrtf((float)cnt[t]) : 0.0f;
        }
    }
    if (j == B - 1 && t == 0) ptr[n] = E;
    __syncthreads();
    if (fits) {
        // replay from recorded ranks
#pragma unroll
        for (int q = 0; q < SITER; q++) {
            int e = t + q * 256;
            if (e < S) {
                int pk = stage[e];
                srt2[cexc[pk >> 17] + rk_[q]] = pk & 0x1FFFF;
            }
        }
    } else {
        int src = t * chunkE + srow[t];
        int len = hrow[t];
        for (int q = 0; q < len; q++) {
            int pk = srt[src + q];
            int pos = atomicAdd(&cexc[pk >> 17], 1);
            srt2[pos] = pk & 0x1FFFF;
        }
    }
}

// p row = 8 uint32 (16 bf16) = 32 B.
template <int FI>
__global__ void proj_kernel(const float* __restrict__ hin, const float* __restrict__ W,
                            const float* __restrict__ dinv, unsigned* __restrict__ p, int n) {
    __shared__ float sW[FI * 16];
    for (int t = threadIdx.x; t < FI * 16; t += blockDim.x) sW[t] = W[t];
    __syncthreads();
    int i = blockIdx.x * blockDim.x + threadIdx.x;
    if (i >= n) return;
    float hi[FI];
    const float4* hr = (const float4*)(hin + (size_t)i * FI);
#pragma unroll
    for (int k = 0; k < FI / 4; k++) {
        float4 v = hr[k];
        hi[4 * k] = v.x; hi[4 * k + 1] = v.y; hi[4 * k + 2] = v.z; hi[4 * k + 3] = v.w;
    }
    float di = dinv[i];
    float outv[16];
#pragma unroll
    for (int f = 0; f < 16; f++) {
        float s = 0.0f;
#pragma unroll
        for (int k = 0; k < FI; k++) s += hi[k] * sW[k * 16 + f];
        outv[f] = s * di;
    }
    uint4 u0, u1;
    u0.x = bf16rte(outv[0])  | (bf16rte(outv[1])  << 16);
    u0.y = bf16rte(outv[2])  | (bf16rte(outv[3])  << 16);
    u0.z = bf16rte(outv[4])  | (bf16rte(outv[5])  << 16);
    u0.w = bf16rte(outv[6])  | (bf16rte(outv[7])  << 16);
    u1.x = bf16rte(outv[8])  | (bf16rte(outv[9])  << 16);
    u1.y = bf16rte(outv[10]) | (bf16rte(outv[11]) << 16);
    u1.z = bf16rte(outv[12]) | (bf16rte(outv[13]) << 16);
    u1.w = bf16rte(outv[14]) | (bf16rte(outv[15]) << 16);
    uint4* pr = (uint4*)(p + (size_t)i * 8);
    pr[0] = u0;
    pr[1] = u1;
}

// 4 lanes per node (natural order): hb = feature half (16B of 32B row), sh =
// edge half. srt2 read via 4-aligned int4 (4x fewer index-load instructions);
// elements outside [e0,e1) masked to zero (neighbor-col entries are valid row
// indices -> p load safe; &0x1FFFF keeps any over-read in-bounds). shfl_xor
// merge; fused finish on sh==0. hin/out may alias (layer 2): a node's h row is
// read only by its own lanes and reads precede stores in wave program order.
template <int FI>
__global__ __launch_bounds__(256, 4)
void gather_finish_kernel(const int* __restrict__ ptr, const int* __restrict__ srt2,
                          const uintv4* __restrict__ p, const float* hin,
                          const float* __restrict__ V, const float* __restrict__ b,
                          const float* __restrict__ dinv, float* out, int n) {
    __shared__ float sV[FI * 16];
    __shared__ float sb[16];
    for (int t = threadIdx.x; t < FI * 16; t += blockDim.x) sV[t] = V[t];
    if (threadIdx.x < 16) sb[threadIdx.x] = b[threadIdx.x];
    __syncthreads();
    int g = blockIdx.x * (blockDim.x >> 2) + (threadIdx.x >> 2);
    int hb = threadIdx.x & 1;
    int sh = (threadIdx.x >> 1) & 1;
    if (g >= n) return;
    int s0 = ptr[g], s1 = ptr[g + 1];
    int mid = (s0 + s1) >> 1;
    int e0 = sh ? mid : s0;
    int e1 = sh ? s1 : mid;
    const uintv4* pb = p + hb;          // lane's half: p[(size_t)r*2 + hb]
    float a0 = 0, a1 = 0, a2 = 0, a3 = 0, a4 = 0, a5 = 0, a6 = 0, a7 = 0;
    for (int a = e0 & ~3; a < e1; a += 8) {
        intv4 w0 = __builtin_nontemporal_load((const intv4*)(srt2 + a));
        intv4 w1 = __builtin_nontemporal_load((const intv4*)(srt2 + a + 4));
        int r[8] = {w0[0], w0[1], w0[2], w0[3], w1[0], w1[1], w1[2], w1[3]};
        uintv4 u[8];
#pragma unroll
        for (int q = 0; q < 8; q++) u[q] = pb[(size_t)(r[q] & 0x1FFFF) * 2];
#pragma unroll
        for (int q = 0; q < 8; q++) {
            int idx = a + q;
            if (idx < e0 || idx >= e1) u[q] = (uintv4)0;  // cndmask-zero
            a0 += __uint_as_float(u[q][0] << 16);
            a1 += __uint_as_float(u[q][0] & 0xFFFF0000u);
            a2 += __uint_as_float(u[q][1] << 16);
            a3 += __uint_as_float(u[q][1] & 0xFFFF0000u);
            a4 += __uint_as_float(u[q][2] << 16);
            a5 += __uint_as_float(u[q][2] & 0xFFFF0000u);
            a6 += __uint_as_float(u[q][3] << 16);
            a7 += __uint_as_float(u[q][3] & 0xFFFF0000u);
        }
    }
    // merge edge halves (lane ^ 2 is the other sh, same hb, same node)
    a0 += __shfl_xor(a0, 2);
    a1 += __shfl_xor(a1, 2);
    a2 += __shfl_xor(a2, 2);
    a3 += __shfl_xor(a3, 2);
    a4 += __shfl_xor(a4, 2);
    a5 += __shfl_xor(a5, 2);
    a6 += __shfl_xor(a6, 2);
    a7 += __shfl_xor(a7, 2);
    if (sh != 0) return;
    // fused finish: h@V + b + dinv*agg, relu (features f0..f0+7)
    int f0 = hb * 8;
    float hi[FI];
    const float4* h4 = (const float4*)(hin + (size_t)g * FI);
#pragma unroll
    for (int k = 0; k < FI / 4; k++) {
        float4 v = h4[k];
        hi[4 * k] = v.x; hi[4 * k + 1] = v.y; hi[4 * k + 2] = v.z; hi[4 * k + 3] = v.w;
    }
    float hv[8] = {0, 0, 0, 0, 0, 0, 0, 0};
#pragma unroll
    for (int k = 0; k < FI; k++) {
        float hk = hi[k];
#pragma unroll
        for (int q = 0; q < 8; q++) hv[q] += hk * sV[k * 16 + f0 + q];
    }
    float di = dinv[g];
    float rr[8] = {a0, a1, a2, a3, a4, a5, a6, a7};
#pragma unroll
    for (int q = 0; q < 8; q++) {
        float r_ = sb[f0 + q] + di * rr[q] + hv[q];
        rr[q] = r_ > 0.0f ? r_ : 0.0f;
    }
    float4* o4 = (float4*)(out + (size_t)g * 16 + f0);
    o4[0] = make_float4(rr[0], rr[1], rr[2], rr[3]);
    o4[1] = make_float4(rr[4], rr[5], rr[6], rr[7]);
}

extern "C" void kernel_launch(void* const* d_in, const int* in_sizes, int n_in,
                              void* d_out, int out_size, void* d_ws, size_t ws_size,
                              hipStream_t stream) {
    const float* x  = (const float*)d_in[0];
    const int*   ei = (const int*)d_in[1];
    const float* W1 = (const float*)d_in[2];
    const float* V1 = (const float*)d_in[3];
    const float* b1 = (const float*)d_in[4];
    const float* W2 = (const float*)d_in[5];
    const float* V2 = (const float*)d_in[6];
    const float* b2 = (const float*)d_in[7];

    const int n = in_sizes[0] / 8;       // 100000 nodes
    const int E = in_sizes[1] / 2;       // 3200000 edges
    const int* row = ei;                 // edge_index[0]
    const int* col = ei + E;             // edge_index[1]

    const int B = (n + WC - 1) / WC;     // 782 buckets
    const int chunkE = (E + NBC - 1) / NBC;  // 12500 (CITER*1024 >= chunkE)

    auto align = [](size_t v) { return (v + 255) / 256 * 256; };
    char* ws = (char*)d_ws;
    size_t off = 0;
    float* dinv  = (float*)(ws + off); off += align((size_t)n * 4);
    int*   ptr   = (int*)(ws + off);   off += align((size_t)(n + 1) * 4);
    int*   histg = (int*)(ws + off);   off += align((size_t)NBC * B * 4);
    int*   segst = (int*)(ws + off);   off += align((size_t)NBC * B * 4);
    int*   part  = (int*)(ws + off);   off += align((size_t)8 * B * 4);
    int*   bbase = (int*)(ws + off);   off += align((size_t)B * 4);
    // srt is dead after bucket_sort; proj writes packed p over the same region.
    int*      srt = (int*)(ws + off);
    unsigned* p   = (unsigned*)(ws + off); off += align((size_t)E * 4);  // E*4 >= n*8*4
    int*      srt2 = (int*)(ws + off);     off += align((size_t)E * 4 + 64);  // +64: int4 over-read pad
    float* out = (float*)d_out;
    // ~28 MB total

    const int bs = 256;
    const int gbN = (n + bs - 1) / bs;
    const int gbG = (n * 4 + bs - 1) / bs;   // gather: 4 lanes per node

    // CSR build (no global atomics; single-writer L2-resident write windows)
    chunk_sort<<<NBC, 1024, 0, stream>>>(row, col, srt, histg, segst, E, B, chunkE);
    tot8_kernel<<<(8 * B + bs - 1) / bs, bs, 0, stream>>>(histg, part, B);
    scan1024_kernel<<<1, 1024, 0, stream>>>(part, bbase, B);
    bucket_sort<<<B, bs, 0, stream>>>(srt, histg, segst, bbase, ptr, srt2, dinv, E, n, B, chunkE);

    // Layer 1 (FI=8): x -> d_out   (proj overwrites srt region with p — srt is dead)
    proj_kernel<8><<<gbN, bs, 0, stream>>>(x, W1, dinv, p, n);
    gather_finish_kernel<8><<<gbG, bs, 0, stream>>>(ptr, srt2, (const uintv4*)p, x, V1, b1, dinv, out, n);

    // Layer 2 (FI=16): d_out -> d_out
    proj_kernel<16><<<gbN, bs, 0, stream>>>(out, W2, dinv, p, n);
    gather_finish_kernel<16><<<gbG, bs, 0, stream>>>(ptr, srt2, (const uintv4*)p, out, V2, b2, dinv, out, n);
}